// Round 7
// baseline (1439.701 us; speedup 1.0000x reference)
//
#include <hip/hip_runtime.h>
#include <hip/hip_bf16.h>

// out = (1-z)*hidden + z*n
//   r = sig(in·(w_ir+w_hr)^T + b_ir+b_hr)
//   z = sig(in·(w_iz+w_hz)^T + b_iz+b_hz)
//   n = sig(in·w_in^T + b_in + r*(in·w_hn^T + b_hn))
// Fast path: prepass folds/converts weights+input to bf16 in d_ws, then an
// m201-style 4-phase fused GEMM with COUNTED vmcnt (T4: never drain to 0 in
// the main loop; K-half staging granularity keeps 4-12 loads in flight).
// Fallback (ws too small): round-1 fp32-staged kernel (known passing).

#define THREADS 512
#define B_DIM 8192
#define D_DIM 4096
#define H_DIM 4096
#define BM 256
#define GBN 64              // per-gate output cols per block
#define BK 64
#define NT (D_DIM / BK)     // 64 K-tiles
#define DBUF 65536          // bytes per LDS buffer: A 32KB + 4x8KB B

// ws layout (bytes)
#define WS_WR 0
#define WS_WZ 33554432
#define WS_WN 67108864
#define WS_WH 100663296
#define WS_A  134217728
#define WS_NEED 201326592ULL

typedef __attribute__((ext_vector_type(8))) short bf16x8;
typedef __attribute__((ext_vector_type(4))) float f32x4;
typedef __attribute__((ext_vector_type(4))) int i32x4;

__device__ __forceinline__ unsigned f2bf(float f) {
    union { float f; unsigned u; } v; v.f = f;
    return (v.u + 0x7FFFu + ((v.u >> 16) & 1u)) >> 16;   // RNE
}
__device__ __forceinline__ unsigned pk(float a, float b) {
    return (f2bf(a) & 0xFFFFu) | (f2bf(b) << 16);
}
__device__ __forceinline__ i32x4 pack8(float4 x, float4 y) {
    i32x4 r;
    r[0] = (int)pk(x.x, x.y); r[1] = (int)pk(x.z, x.w);
    r[2] = (int)pk(y.x, y.y); r[3] = (int)pk(y.z, y.w);
    return r;
}
__device__ __forceinline__ float sigmoidf_(float x) {
    return 1.0f / (1.0f + __expf(-x));
}
__device__ __forceinline__ void gld16(const void* g, void* l) {
    __builtin_amdgcn_global_load_lds(
        (const __attribute__((address_space(1))) unsigned*)g,
        (__attribute__((address_space(3))) unsigned*)l, 16, 0, 0);
}

// ---------------- prepass kernels ----------------
__global__ __launch_bounds__(256) void prep_w(
    const float* __restrict__ ir, const float* __restrict__ hr,
    const float* __restrict__ iz, const float* __restrict__ hz,
    const float* __restrict__ inw, const float* __restrict__ hn,
    i32x4* __restrict__ wr, i32x4* __restrict__ wz,
    i32x4* __restrict__ wn, i32x4* __restrict__ wh)
{
    const int i = blockIdx.x * 256 + threadIdx.x;     // chunk of 8 floats
    const float4* pir = (const float4*)ir; const float4* phr = (const float4*)hr;
    const float4* piz = (const float4*)iz; const float4* phz = (const float4*)hz;
    const float4* pin = (const float4*)inw; const float4* phn = (const float4*)hn;
    float4 a0 = pir[2*i], a1 = pir[2*i+1], b0 = phr[2*i], b1 = phr[2*i+1];
    wr[i] = pack8(a0 + b0, a1 + b1);
    a0 = piz[2*i]; a1 = piz[2*i+1]; b0 = phz[2*i]; b1 = phz[2*i+1];
    wz[i] = pack8(a0 + b0, a1 + b1);
    wn[i] = pack8(pin[2*i], pin[2*i+1]);
    wh[i] = pack8(phn[2*i], phn[2*i+1]);
}

__global__ __launch_bounds__(256) void prep_a(const float* __restrict__ in,
                                              i32x4* __restrict__ a)
{
    const int i = blockIdx.x * 256 + threadIdx.x;
    const float4* p = (const float4*)in;
    a[i] = pack8(p[2*i], p[2*i+1]);
}

// ---------------- main bf16 kernel (4-phase, counted vmcnt) ----------------
// LDS per buffer (64 KB):
//   A  [0, 32K):  frag(mfr 0..15, kk 0..1) at (mfr*2+kk)*1024
//   Bg [32K+g*8K, +8K): frag(nfr 0..3, kk) at (nfr*2+kk)*1024
// Frag = 16 rows x 32 k bf16, 1 KB, lane slot l = (row l&15, k-chunk l>>4):
// linear in MFMA lane order -> DMA writes AND ds_read_b128 conflict-free.
//
// Half X(t) = all kk0 frags (32KB), half Y(t) = all kk1 frags.
// Per wave per half: 2 A-frags (mfr 2w,2w+1) + 2 B-frags (g=w>>1, nfr
// (w&1)*2,(w&1)*2+1) = 4 gld16.
// Steady-state outstanding gld16 per thread: 4 -> 8 -> 12 -> (vmcnt 8) -> 8
// -> (vmcnt 4) -> 4. NEVER drained to 0 except at the final tile.
__global__ __launch_bounds__(THREADS, 2) void gru_bf16(
    const char* __restrict__ Abf, const char* __restrict__ Wr,
    const char* __restrict__ Wz, const char* __restrict__ Wn,
    const char* __restrict__ Wh,
    const float* __restrict__ hidden,
    const float* __restrict__ b_ir, const float* __restrict__ b_iz,
    const float* __restrict__ b_in, const float* __restrict__ b_hr,
    const float* __restrict__ b_hz, const float* __restrict__ b_hn,
    float* __restrict__ out)
{
    __shared__ __attribute__((aligned(128))) char smem[2 * DBUF];

    const int tid  = threadIdx.x;
    const int lane = tid & 63;
    const int wid  = tid >> 6;
    const int wm   = wid >> 2;     // 0..1 : M-half (128 rows)
    const int wn   = wid & 3;      // 0..3 : 16-col slice (nfr = wn)

    // linear, b-fastest: consecutive blocks share the weight panel; A L3-hot.
    const int nb   = (int)blockIdx.x;
    const int bblk = nb & 31;       // 32 b-blocks
    const int hblk = nb >> 5;       // 64 h-blocks
    const int b0 = bblk * BM;
    const int h0 = hblk * GBN;

    // staging roles (per wave): A-frags mfr = 2w, 2w+1; B gate sg = w>>1,
    // nfr = (w&1)*2, (w&1)*2+1.
    const int sg  = wid >> 1;
    const int sn0 = (wid & 1) * 2;
    const char* gWsel = (sg == 0) ? Wr : (sg == 1) ? Wz : (sg == 2) ? Wn : Wh;
    const char* pA0 = Abf + (size_t)(b0 + (wid * 2) * 16 + (lane & 15)) * 8192 + ((lane >> 4) * 16);
    const char* pA1 = pA0 + 131072;   // next 16 rows
    const char* pB0 = gWsel + (size_t)(h0 + sn0 * 16 + (lane & 15)) * 8192 + ((lane >> 4) * 16);
    const char* pB1 = pB0 + 131072;
    const int dA0 = (wid * 2) * 2048;          // frag (2w, kk) base
    const int dA1 = dA0 + 2048;
    const int dB0 = 32768 + sg * 8192 + sn0 * 2048;
    const int dB1 = dB0 + 2048;

    f32x4 acc[4][8];
#pragma unroll
    for (int g = 0; g < 4; ++g)
#pragma unroll
        for (int m = 0; m < 8; ++m) acc[g][m] = (f32x4)0.0f;

    // stage one K-half (kk) of tile t into dbuf d: 4 gld16
#define STAGE_HALF(t, d, kk) do {                                          \
        const size_t ko = (size_t)(t) * 128 + (kk) * 64;                   \
        gld16(pA0 + ko, smem + (d) + dA0 + (kk) * 1024);                   \
        gld16(pA1 + ko, smem + (d) + dA1 + (kk) * 1024);                   \
        gld16(pB0 + ko, smem + (d) + dB0 + (kk) * 1024);                   \
        gld16(pB1 + ko, smem + (d) + dB1 + (kk) * 1024);                   \
    } while (0)

#define RD_AF(kk) do {                                                     \
        _Pragma("unroll")                                                  \
        for (int mf = 0; mf < 8; ++mf)                                     \
            af[mf] = *(const bf16x8*)(cb + ((wm * 8 + mf) * 2 + (kk)) * 1024 + (lane << 4)); \
    } while (0)

#define RD_FB(g, kk)                                                       \
        fb[g] = *(const bf16x8*)(cb + 32768 + (g) * 8192 + (wn * 2 + (kk)) * 1024 + (lane << 4))

#define MM(acc_, a_, b_) acc_ = __builtin_amdgcn_mfma_f32_16x16x32_bf16(a_, b_, acc_, 0, 0, 0)

#define LGKM0 do { asm volatile("s_waitcnt lgkmcnt(0)" ::: "memory");      \
                   __builtin_amdgcn_sched_barrier(0); } while (0)

#define MFMA16(g0_) do {                                                   \
        __builtin_amdgcn_s_setprio(1);                                     \
        _Pragma("unroll")                                                  \
        for (int g = (g0_); g < (g0_) + 2; ++g)                            \
            _Pragma("unroll")                                              \
            for (int mf = 0; mf < 8; ++mf)                                 \
                MM(acc[g][mf], af[mf], fb[g]);                             \
        __builtin_amdgcn_s_setprio(0);                                     \
    } while (0)

    // ---- prologue: stage tile 0 (both halves) into dbuf0 ----
    STAGE_HALF(0, 0, 0);
    STAGE_HALF(0, 0, 1);
    asm volatile("s_waitcnt vmcnt(4)" ::: "memory");   // X(0) done; Y(0) in flight
    __builtin_amdgcn_sched_barrier(0);
    __builtin_amdgcn_s_barrier();

#pragma unroll 1
    for (int t = 0; t < NT; ++t) {
        const int p = t & 1;
        const char* cb = smem + p * DBUF;
        const int d = (p ^ 1) * DBUF;
        const bool stg = (t < NT - 1);
        bf16x8 af[8], fb[4];

        // ---- ph1: kk0, gates 0,1 ; stage X(t+1) ----
        RD_AF(0);
        RD_FB(0, 0); RD_FB(1, 0);
        if (stg) STAGE_HALF(t + 1, d, 0);
        __builtin_amdgcn_s_barrier();
        LGKM0;
        MFMA16(0);

        // ---- ph2: kk0, gates 2,3 ; stage Y(t+1) ----
        RD_FB(2, 0); RD_FB(3, 0);
        if (stg) STAGE_HALF(t + 1, d, 1);
        __builtin_amdgcn_s_barrier();
        LGKM0;
        MFMA16(2);

        // ---- counted drain: Y(t) landed (issued 5 phases ago) ----
        if (stg) { asm volatile("s_waitcnt vmcnt(8)" ::: "memory"); }
        else     { asm volatile("s_waitcnt vmcnt(0)" ::: "memory"); }
        __builtin_amdgcn_sched_barrier(0);
        __builtin_amdgcn_s_barrier();

        // ---- ph3: kk1, gates 0,1 ----
        RD_AF(1);
        RD_FB(0, 1); RD_FB(1, 1);
        LGKM0;
        MFMA16(0);

        // ---- ph4: kk1, gates 2,3 ----
        RD_FB(2, 1); RD_FB(3, 1);
        __builtin_amdgcn_s_barrier();
        LGKM0;
        MFMA16(2);

        // ---- counted drain: X(t+1) landed; Y(t+1) stays in flight ----
        if (stg) { asm volatile("s_waitcnt vmcnt(4)" ::: "memory");
                   __builtin_amdgcn_sched_barrier(0); }
        __builtin_amdgcn_s_barrier();
    }

    // ---- epilogue: biases + gate math + combine, fp32 out ----
    const int r4 = (lane >> 4) * 4;
    const int cn = lane & 15;
    {
        const int h = h0 + wn * 16 + cn;
        const float br = b_ir[h] + b_hr[h];
        const float bz = b_iz[h] + b_hz[h];
        const float bn = b_in[h];
        const float bh = b_hn[h];
#pragma unroll
        for (int m = 0; m < 8; ++m) {
            const int brow = b0 + wm * 128 + m * 16 + r4;
#pragma unroll
            for (int j = 0; j < 4; ++j) {
                const size_t idx = (size_t)(brow + j) * H_DIM + h;
                const float r = sigmoidf_(acc[0][m][j] + br);
                const float z = sigmoidf_(acc[1][m][j] + bz);
                const float n = sigmoidf_(acc[2][m][j] + bn + r * (acc[3][m][j] + bh));
                out[idx] = (1.0f - z) * hidden[idx] + z * n;
            }
        }
    }
#undef STAGE_HALF
#undef RD_AF
#undef RD_FB
#undef MM
#undef LGKM0
#undef MFMA16
}

// ---------------- fallback: round-1 fp32-staged kernel (known passing) ----------------
__global__ __launch_bounds__(THREADS, 2) void gru_fused_f32(
    const float* __restrict__ input, const float* __restrict__ hidden,
    const float* __restrict__ w_ir, const float* __restrict__ b_ir,
    const float* __restrict__ w_iz, const float* __restrict__ b_iz,
    const float* __restrict__ w_in, const float* __restrict__ b_in,
    const float* __restrict__ w_hr, const float* __restrict__ b_hr,
    const float* __restrict__ w_hz, const float* __restrict__ b_hz,
    const float* __restrict__ w_hn, const float* __restrict__ b_hn,
    float* __restrict__ out)
{
    __shared__ int smem[2 * 10240];
    const int tid  = threadIdx.x;
    const int lane = tid & 63;
    const int wid  = tid >> 6;
    const int wm   = wid >> 2;
    const int wn   = wid & 3;
    const int bblk = blockIdx.x & 63;
    const int hblk = blockIdx.x >> 6;
    const int b0 = bblk * 128;
    const int h0 = hblk * 128;
    const int srow = tid >> 2;
    const int sc   = tid & 3;
    const float4* gA  = (const float4*)(input + (size_t)(b0 + srow) * D_DIM + sc * 8);
    const size_t woff = (size_t)(h0 + srow) * D_DIM + sc * 8;
    const float4* gIr = (const float4*)(w_ir + woff);
    const float4* gHr = (const float4*)(w_hr + woff);
    const float4* gIz = (const float4*)(w_iz + woff);
    const float4* gHz = (const float4*)(w_hz + woff);
    const float4* gIn = (const float4*)(w_in + woff);
    const float4* gHn = (const float4*)(w_hn + woff);
    const int wr_ints = (srow >> 4) * 256 + ((sc * 16 + (srow & 15)) * 4);

    f32x4 accR[4][2], accZ[4][2], accN[4][2], accH[4][2];
#pragma unroll
    for (int mf = 0; mf < 4; ++mf)
#pragma unroll
        for (int nf = 0; nf < 2; ++nf) {
            accR[mf][nf] = (f32x4)0.0f; accZ[mf][nf] = (f32x4)0.0f;
            accN[mf][nf] = (f32x4)0.0f; accH[mf][nf] = (f32x4)0.0f;
        }
    float4 La0, La1, Lr0, Lr1, Lr2, Lr3, Lz0, Lz1, Lz2, Lz3, Ln0, Ln1, Lh0, Lh1;
#define LOADREGS(s) do { const int o = (s) * 8;                          \
        La0 = gA[o];  La1 = gA[o + 1];                                   \
        Lr0 = gIr[o]; Lr1 = gIr[o + 1]; Lr2 = gHr[o]; Lr3 = gHr[o + 1];  \
        Lz0 = gIz[o]; Lz1 = gIz[o + 1]; Lz2 = gHz[o]; Lz3 = gHz[o + 1];  \
        Ln0 = gIn[o]; Ln1 = gIn[o + 1];                                  \
        Lh0 = gHn[o]; Lh1 = gHn[o + 1]; } while (0)
#define WRITELDS(pp) do { const int wb = (pp) * 10240 + wr_ints;          \
        *(i32x4*)&smem[wb]        = pack8(La0, La1);                      \
        *(i32x4*)&smem[wb + 2048] = pack8(Lr0 + Lr2, Lr1 + Lr3);          \
        *(i32x4*)&smem[wb + 4096] = pack8(Lz0 + Lz2, Lz1 + Lz3);          \
        *(i32x4*)&smem[wb + 6144] = pack8(Ln0, Ln1);                      \
        *(i32x4*)&smem[wb + 8192] = pack8(Lh0, Lh1); } while (0)
#define COMPUTE(pp) do {                                                  \
        const int cb = (pp) * 10240;                                      \
        const bf16x8* Af = (const bf16x8*)&smem[cb];                      \
        const bf16x8* Br = (const bf16x8*)&smem[cb + 2048];               \
        const bf16x8* Bz = (const bf16x8*)&smem[cb + 4096];               \
        const bf16x8* Bn = (const bf16x8*)&smem[cb + 6144];               \
        const bf16x8* Bh = (const bf16x8*)&smem[cb + 8192];               \
        bf16x8 afr[4];                                                    \
        _Pragma("unroll")                                                 \
        for (int mf = 0; mf < 4; ++mf)                                    \
            afr[mf] = Af[(wm * 4 + mf) * 64 + lane];                      \
        _Pragma("unroll")                                                 \
        for (int nf = 0; nf < 2; ++nf) {                                  \
            const int bi = (wn * 2 + nf) * 64 + lane;                     \
            bf16x8 fr = Br[bi], fz = Bz[bi], fn = Bn[bi], fh = Bh[bi];    \
            _Pragma("unroll")                                             \
            for (int mf = 0; mf < 4; ++mf) {                              \
                accR[mf][nf] = __builtin_amdgcn_mfma_f32_16x16x32_bf16(afr[mf], fr, accR[mf][nf], 0, 0, 0); \
                accZ[mf][nf] = __builtin_amdgcn_mfma_f32_16x16x32_bf16(afr[mf], fz, accZ[mf][nf], 0, 0, 0); \
                accN[mf][nf] = __builtin_amdgcn_mfma_f32_16x16x32_bf16(afr[mf], fn, accN[mf][nf], 0, 0, 0); \
                accH[mf][nf] = __builtin_amdgcn_mfma_f32_16x16x32_bf16(afr[mf], fh, accH[mf][nf], 0, 0, 0); \
            }                                                             \
        } } while (0)
    LOADREGS(0);
    WRITELDS(0);
    __syncthreads();
#pragma unroll 1
    for (int s = 0; s < 128; ++s) {
        if (s + 1 < 128) LOADREGS(s + 1);
        COMPUTE(s & 1);
        if (s + 1 < 128) { WRITELDS((s + 1) & 1); __syncthreads(); }
    }
    const int r4 = (lane >> 4) * 4;
    const int cn = lane & 15;
#pragma unroll
    for (int nf = 0; nf < 2; ++nf) {
        const int h = h0 + wn * 32 + nf * 16 + cn;
        const float br = b_ir[h] + b_hr[h];
        const float bz = b_iz[h] + b_hz[h];
        const float bn = b_in[h];
        const float bh = b_hn[h];
#pragma unroll
        for (int mf = 0; mf < 4; ++mf) {
            const int brow = b0 + wm * 64 + mf * 16 + r4;
#pragma unroll
            for (int j = 0; j < 4; ++j) {
                const size_t idx = (size_t)(brow + j) * H_DIM + h;
                const float r = sigmoidf_(accR[mf][nf][j] + br);
                const float z = sigmoidf_(accZ[mf][nf][j] + bz);
                const float n = sigmoidf_(accN[mf][nf][j] + bn + r * (accH[mf][nf][j] + bh));
                out[idx] = (1.0f - z) * hidden[idx] + z * n;
            }
        }
    }
#undef LOADREGS
#undef WRITELDS
#undef COMPUTE
}

extern "C" void kernel_launch(void* const* d_in, const int* in_sizes, int n_in,
                              void* d_out, int out_size, void* d_ws, size_t ws_size,
                              hipStream_t stream) {
    const float* input  = (const float*)d_in[0];
    const float* hidden = (const float*)d_in[1];
    const float* w_ir = (const float*)d_in[2];  const float* b_ir = (const float*)d_in[3];
    const float* w_iz = (const float*)d_in[4];  const float* b_iz = (const float*)d_in[5];
    const float* w_in = (const float*)d_in[6];  const float* b_in = (const float*)d_in[7];
    const float* w_hr = (const float*)d_in[8];  const float* b_hr = (const float*)d_in[9];
    const float* w_hz = (const float*)d_in[10]; const float* b_hz = (const float*)d_in[11];
    const float* w_hn = (const float*)d_in[12]; const float* b_hn = (const float*)d_in[13];
    float* out = (float*)d_out;

    if (ws_size >= WS_NEED) {
        char* ws = (char*)d_ws;
        prep_w<<<dim3(8192), dim3(256), 0, stream>>>(
            w_ir, w_hr, w_iz, w_hz, w_in, w_hn,
            (i32x4*)(ws + WS_WR), (i32x4*)(ws + WS_WZ),
            (i32x4*)(ws + WS_WN), (i32x4*)(ws + WS_WH));
        prep_a<<<dim3(16384), dim3(256), 0, stream>>>(input, (i32x4*)(ws + WS_A));
        gru_bf16<<<dim3((B_DIM / BM) * (H_DIM / GBN)), dim3(THREADS), 0, stream>>>(
            ws + WS_A, ws + WS_WR, ws + WS_WZ, ws + WS_WN, ws + WS_WH,
            hidden, b_ir, b_iz, b_in, b_hr, b_hz, b_hn, out);
    } else {
        gru_fused_f32<<<dim3(2048), dim3(THREADS), 0, stream>>>(
            input, hidden, w_ir, b_ir, w_iz, b_iz, w_in, b_in,
            w_hr, b_hr, w_hz, b_hz, w_hn, b_hn, out);
    }
}

// Round 8
// 1013.482 us; speedup vs baseline: 1.4205x; 1.4205x over previous
//
#include <hip/hip_runtime.h>
#include <hip/hip_bf16.h>

// out = (1-z)*hidden + z*n
//   r = sig(in·(w_ir+w_hr)^T + b_ir+b_hr)
//   z = sig(in·(w_iz+w_hz)^T + b_iz+b_hz)
//   n = sig(in·w_in^T + b_in + r*(in·w_hn^T + b_hn))
// Fast path: prepass folds/converts weights+input to bf16 in d_ws **in LDS-
// fragment order** (so every global_load_lds reads 1KB CONTIGUOUS global and
// writes 1KB linear LDS), then the round-6 4-phase fused GEMM (BM=256,BK=64,
// per-gate BN=64, 8 waves, 128KB LDS dbuf) with schedule unchanged.
// Fallback (ws too small): round-1 fp32-staged kernel (known passing).

#define THREADS 512
#define B_DIM 8192
#define D_DIM 4096
#define H_DIM 4096
#define BM 256
#define GBN 64              // per-gate output cols per block
#define BK 64
#define NT (D_DIM / BK)     // 64 K-tiles
#define DBUF 65536          // bytes per LDS buffer: A 32KB + 4x8KB B

// ws layout (bytes)
#define WS_WR 0
#define WS_WZ 33554432
#define WS_WN 67108864
#define WS_WH 100663296
#define WS_A  134217728
#define WS_NEED 201326592ULL

typedef __attribute__((ext_vector_type(8))) short bf16x8;
typedef __attribute__((ext_vector_type(4))) float f32x4;
typedef __attribute__((ext_vector_type(4))) int i32x4;

__device__ __forceinline__ unsigned f2bf(float f) {
    union { float f; unsigned u; } v; v.f = f;
    return (v.u + 0x7FFFu + ((v.u >> 16) & 1u)) >> 16;   // RNE
}
__device__ __forceinline__ unsigned pk(float a, float b) {
    return (f2bf(a) & 0xFFFFu) | (f2bf(b) << 16);
}
__device__ __forceinline__ i32x4 pack8(float4 x, float4 y) {
    i32x4 r;
    r[0] = (int)pk(x.x, x.y); r[1] = (int)pk(x.z, x.w);
    r[2] = (int)pk(y.x, y.y); r[3] = (int)pk(y.z, y.w);
    return r;
}
__device__ __forceinline__ float sigmoidf_(float x) {
    return 1.0f / (1.0f + __expf(-x));
}
__device__ __forceinline__ void gld16(const void* g, void* l) {
    __builtin_amdgcn_global_load_lds(
        (const __attribute__((address_space(1))) unsigned*)g,
        (__attribute__((address_space(3))) unsigned*)l, 16, 0, 0);
}

// ---------------- prepass: fold/convert + permute into fragment order -----
// W gate layout (32MB each): [hblk 0..63][t 0..63][nfr 0..3][kk 0..1][C 0..3][R 0..15][16B]
//   addr = hblk*524288 + t*8192 + nfr*2048 + kk*1024 + C*256 + R*16
// A layout (64MB): [bblk 0..31][t 0..63][mfr 0..15][kk][C][R][16B]
//   addr = bblk*2097152 + t*32768 + mfr*2048 + kk*1024 + C*256 + R*16
// Thread map: tx -> (R = tx&15, c8loc = tx>>4); bx -> (c8blk = bx&31, rowgrp = bx>>5).
// row = rowgrp*16 + R; c8 = c8blk*16 + c8loc (c8 = k/8).
// Reads: 16 rows' lines fully consumed within the block (L2-local).
// Writes: lanes (R fast, then c8loc) -> 1KB contiguous per 64-lane wave.
__global__ __launch_bounds__(256) void prep_w_t(
    const float* __restrict__ ir, const float* __restrict__ hr,
    const float* __restrict__ iz, const float* __restrict__ hz,
    const float* __restrict__ inw, const float* __restrict__ hn,
    char* __restrict__ wsbase)
{
    const int tx = threadIdx.x;
    const int R = tx & 15;
    const int c8loc = tx >> 4;
    const int bx = blockIdx.x;
    const int c8blk = bx & 31;
    const int hgrp = bx >> 5;
    const int gy = blockIdx.y;
    const int h  = hgrp * 16 + R;
    const int c8 = c8blk * 16 + c8loc;

    const float* s1 = (gy == 0) ? ir : (gy == 1) ? iz : (gy == 2) ? inw : hn;
    const size_t fi = ((size_t)h * 512 + c8) * 2;   // float4 index
    const float4* p1 = (const float4*)s1;
    float4 a0 = p1[fi], a1 = p1[fi + 1];
    if (gy < 2) {
        const float4* p2 = (const float4*)((gy == 0) ? hr : hz);
        a0 = a0 + p2[fi];
        a1 = a1 + p2[fi + 1];
    }
    const i32x4 v = pack8(a0, a1);
    const int hblk = h >> 6, nfr = (h >> 4) & 3;
    const int t = c8 >> 3, K = (c8 >> 2) & 1, C = c8 & 3;
    const size_t addr = (size_t)gy * 33554432 + (size_t)hblk * 524288
                      + (size_t)t * 8192 + nfr * 2048 + K * 1024 + C * 256 + R * 16;
    *(i32x4*)(wsbase + addr) = v;
}

__global__ __launch_bounds__(256) void prep_a_t(const float* __restrict__ in,
                                                char* __restrict__ abase)
{
    const int tx = threadIdx.x;
    const int R = tx & 15;
    const int c8loc = tx >> 4;
    const int bx = blockIdx.x;
    const int c8blk = bx & 31;
    const int bgrp = bx >> 5;
    const int b  = bgrp * 16 + R;
    const int c8 = c8blk * 16 + c8loc;

    const size_t fi = ((size_t)b * 512 + c8) * 2;
    const float4* p = (const float4*)in;
    const i32x4 v = pack8(p[fi], p[fi + 1]);
    const int bblk = b >> 8, mfr = (b >> 4) & 15;
    const int t = c8 >> 3, K = (c8 >> 2) & 1, C = c8 & 3;
    const size_t addr = (size_t)bblk * 2097152 + (size_t)t * 32768
                      + mfr * 2048 + K * 1024 + C * 256 + R * 16;
    *(i32x4*)(abase + addr) = v;
}

// ---------------- main bf16 kernel (round-6 schedule, contiguous staging) --
// LDS per buffer (64 KB):
//   A  [0, 32K):  frag(mfr 0..15, kk 0..1) at (mfr*2+kk)*1024
//   Bg [32K+g*8K, +8K): frag(nfr 0..3, kk) at (nfr*2+kk)*1024
// Frag = 16 rows x 32 k bf16, 1 KB, lane l = (C = l>>4, R = l&15) -> linear in
// MFMA lane order. Staging sources are fragment-ordered in ws, so each gld16
// reads 1KB contiguous AND writes 1KB linear LDS. ds_read_b128 conflict-free.
//
// Per K-tile t (reads dbuf p=t&1; stages tile t+1 into dbuf p^1):
//  ph1: rd af[mh0](8) + fb[g0,g1](4) | stage A(t+1): 4 gld16 | bar lgkm0 prio1 16MM
//  ph2: rd fb[g2,g3](4)              | stage B(t+1): 4 gld16 | bar lgkm0 prio1 16MM
//  ph3: rd af[mh1](8)                |                       | bar lgkm0 prio1 16MM
//  ph4:                              |                       | bar prio1 16MM
//       vmcnt(0) ; bar   (round-6 boundary, unchanged)
__global__ __launch_bounds__(THREADS, 2) void gru_bf16(
    const char* __restrict__ Abf, const char* __restrict__ Wr,
    const char* __restrict__ Wz, const char* __restrict__ Wn,
    const char* __restrict__ Wh,
    const float* __restrict__ hidden,
    const float* __restrict__ b_ir, const float* __restrict__ b_iz,
    const float* __restrict__ b_in, const float* __restrict__ b_hr,
    const float* __restrict__ b_hz, const float* __restrict__ b_hn,
    float* __restrict__ out)
{
    __shared__ __attribute__((aligned(128))) char smem[2 * DBUF];

    const int tid  = threadIdx.x;
    const int lane = tid & 63;
    const int wid  = tid >> 6;
    const int wm   = wid >> 2;     // 0..1 : M-half (128 rows)
    const int wn   = wid & 3;      // 0..3 : 16-col slice (nfr = wn)

    // linear, b-fastest: consecutive blocks share the weight panel; A L3-hot.
    const int nb   = (int)blockIdx.x;
    const int bblk = nb & 31;       // 32 b-blocks
    const int hblk = nb >> 5;       // 64 h-blocks
    const int b0 = bblk * BM;
    const int h0 = hblk * GBN;

    // staging roles (per wave): A-frags mfr = 2w, 2w+1 (4KB contiguous);
    // B gate sg = w>>1, nfr = (w&1)*2, +1 (4KB contiguous).
    const int sg  = wid >> 1;
    const int sn0 = (wid & 1) * 2;
    const char* gWsel = (sg == 0) ? Wr : (sg == 1) ? Wz : (sg == 2) ? Wn : Wh;
    const char* pA = Abf + (size_t)bblk * 2097152 + (size_t)(2 * wid) * 2048 + (lane << 4);
    const char* pB = gWsel + (size_t)hblk * 524288 + (size_t)sn0 * 2048 + (lane << 4);
    const int dA = (2 * wid) * 2048;
    const int dB = 32768 + sg * 8192 + sn0 * 2048;

    f32x4 acc[4][8];
#pragma unroll
    for (int g = 0; g < 4; ++g)
#pragma unroll
        for (int m = 0; m < 8; ++m) acc[g][m] = (f32x4)0.0f;

#define STAGE_A(t, d) do { const size_t ko = (size_t)(t) * 32768;              \
        gld16(pA + ko,        smem + (d) + dA);                                \
        gld16(pA + ko + 1024, smem + (d) + dA + 1024);                         \
        gld16(pA + ko + 2048, smem + (d) + dA + 2048);                         \
        gld16(pA + ko + 3072, smem + (d) + dA + 3072);                         \
    } while (0)

#define STAGE_B(t, d) do { const size_t ko = (size_t)(t) * 8192;               \
        gld16(pB + ko,        smem + (d) + dB);                                \
        gld16(pB + ko + 1024, smem + (d) + dB + 1024);                         \
        gld16(pB + ko + 2048, smem + (d) + dB + 2048);                         \
        gld16(pB + ko + 3072, smem + (d) + dB + 3072);                         \
    } while (0)

#define RD_AF(mhq) do {                                                        \
        _Pragma("unroll")                                                      \
        for (int mf = 0; mf < 4; ++mf)                                         \
            _Pragma("unroll")                                                  \
            for (int kk = 0; kk < 2; ++kk)                                     \
                af[mf][kk] = *(const bf16x8*)(cb + ((wm * 8 + (mhq) * 4 + mf) * 2 + kk) * 1024 + (lane << 4)); \
    } while (0)

#define RD_FB(g) do {                                                          \
        _Pragma("unroll")                                                      \
        for (int kk = 0; kk < 2; ++kk)                                         \
            fb[g][kk] = *(const bf16x8*)(cb + 32768 + (g) * 8192 + (wn * 2 + kk) * 1024 + (lane << 4)); \
    } while (0)

#define MM(acc_, a_, b_) acc_ = __builtin_amdgcn_mfma_f32_16x16x32_bf16(a_, b_, acc_, 0, 0, 0)

#define PH_MFMA(g0_, ab_) do {                                                 \
        __builtin_amdgcn_s_barrier();                                          \
        asm volatile("s_waitcnt lgkmcnt(0)" ::: "memory");                     \
        __builtin_amdgcn_sched_barrier(0);                                     \
        __builtin_amdgcn_s_setprio(1);                                         \
        _Pragma("unroll")                                                      \
        for (int g = (g0_); g < (g0_) + 2; ++g)                                \
            _Pragma("unroll")                                                  \
            for (int mf = 0; mf < 4; ++mf)                                     \
                _Pragma("unroll")                                              \
                for (int kk = 0; kk < 2; ++kk)                                 \
                    MM(acc[g][(ab_) * 4 + mf], af[mf][kk], fb[g][kk]);         \
        __builtin_amdgcn_s_setprio(0);                                         \
    } while (0)

    // ---- prologue: stage tile 0 into dbuf0 ----
    STAGE_A(0, 0);
    STAGE_B(0, 0);
    asm volatile("s_waitcnt vmcnt(0)" ::: "memory");
    __builtin_amdgcn_s_barrier();

#pragma unroll 1
    for (int t = 0; t < NT; ++t) {
        const int p = t & 1;
        const char* cb = smem + p * DBUF;
        const int d = (p ^ 1) * DBUF;
        const bool stg = (t < NT - 1);
        bf16x8 af[4][2], fb[4][2];

        // ---- ph1: af[mh0], fb[g0,g1]; stage A(t+1) ----
        RD_AF(0);
        RD_FB(0); RD_FB(1);
        if (stg) STAGE_A(t + 1, d);
        PH_MFMA(0, 0);

        // ---- ph2: fb[g2,g3]; stage B(t+1) ----
        RD_FB(2); RD_FB(3);
        if (stg) STAGE_B(t + 1, d);
        PH_MFMA(2, 0);

        // ---- ph3: af[mh1] ----
        RD_AF(1);
        PH_MFMA(0, 1);

        // ---- ph4 ----
        PH_MFMA(2, 1);

        // tile boundary: publish t+1's stages (issued 2-3 phases ago)
        if (stg) { asm volatile("s_waitcnt vmcnt(0)" ::: "memory"); }
        __builtin_amdgcn_s_barrier();
    }

    // ---- epilogue: biases + gate math + combine, fp32 out ----
    const int r4 = (lane >> 4) * 4;
    const int cn = lane & 15;
    {
        const int h = h0 + wn * 16 + cn;
        const float br = b_ir[h] + b_hr[h];
        const float bz = b_iz[h] + b_hz[h];
        const float bn = b_in[h];
        const float bh = b_hn[h];
#pragma unroll
        for (int m = 0; m < 8; ++m) {
            const int brow = b0 + wm * 128 + m * 16 + r4;
#pragma unroll
            for (int j = 0; j < 4; ++j) {
                const size_t idx = (size_t)(brow + j) * H_DIM + h;
                const float r = sigmoidf_(acc[0][m][j] + br);
                const float z = sigmoidf_(acc[1][m][j] + bz);
                const float n = sigmoidf_(acc[2][m][j] + bn + r * (acc[3][m][j] + bh));
                out[idx] = (1.0f - z) * hidden[idx] + z * n;
            }
        }
    }
#undef STAGE_A
#undef STAGE_B
#undef RD_AF
#undef RD_FB
#undef MM
#undef PH_MFMA
}

// ---------------- fallback: round-1 fp32-staged kernel (known passing) ----------------
__global__ __launch_bounds__(THREADS, 2) void gru_fused_f32(
    const float* __restrict__ input, const float* __restrict__ hidden,
    const float* __restrict__ w_ir, const float* __restrict__ b_ir,
    const float* __restrict__ w_iz, const float* __restrict__ b_iz,
    const float* __restrict__ w_in, const float* __restrict__ b_in,
    const float* __restrict__ w_hr, const float* __restrict__ b_hr,
    const float* __restrict__ w_hz, const float* __restrict__ b_hz,
    const float* __restrict__ w_hn, const float* __restrict__ b_hn,
    float* __restrict__ out)
{
    __shared__ int smem[2 * 10240];
    const int tid  = threadIdx.x;
    const int lane = tid & 63;
    const int wid  = tid >> 6;
    const int wm   = wid >> 2;
    const int wn   = wid & 3;
    const int bblk = blockIdx.x & 63;
    const int hblk = blockIdx.x >> 6;
    const int b0 = bblk * 128;
    const int h0 = hblk * 128;
    const int srow = tid >> 2;
    const int sc   = tid & 3;
    const float4* gA  = (const float4*)(input + (size_t)(b0 + srow) * D_DIM + sc * 8);
    const size_t woff = (size_t)(h0 + srow) * D_DIM + sc * 8;
    const float4* gIr = (const float4*)(w_ir + woff);
    const float4* gHr = (const float4*)(w_hr + woff);
    const float4* gIz = (const float4*)(w_iz + woff);
    const float4* gHz = (const float4*)(w_hz + woff);
    const float4* gIn = (const float4*)(w_in + woff);
    const float4* gHn = (const float4*)(w_hn + woff);
    const int wr_ints = (srow >> 4) * 256 + ((sc * 16 + (srow & 15)) * 4);

    f32x4 accR[4][2], accZ[4][2], accN[4][2], accH[4][2];
#pragma unroll
    for (int mf = 0; mf < 4; ++mf)
#pragma unroll
        for (int nf = 0; nf < 2; ++nf) {
            accR[mf][nf] = (f32x4)0.0f; accZ[mf][nf] = (f32x4)0.0f;
            accN[mf][nf] = (f32x4)0.0f; accH[mf][nf] = (f32x4)0.0f;
        }
    float4 La0, La1, Lr0, Lr1, Lr2, Lr3, Lz0, Lz1, Lz2, Lz3, Ln0, Ln1, Lh0, Lh1;
#define LOADREGS(s) do { const int o = (s) * 8;                          \
        La0 = gA[o];  La1 = gA[o + 1];                                   \
        Lr0 = gIr[o]; Lr1 = gIr[o + 1]; Lr2 = gHr[o]; Lr3 = gHr[o + 1];  \
        Lz0 = gIz[o]; Lz1 = gIz[o + 1]; Lz2 = gHz[o]; Lz3 = gHz[o + 1];  \
        Ln0 = gIn[o]; Ln1 = gIn[o + 1];                                  \
        Lh0 = gHn[o]; Lh1 = gHn[o + 1]; } while (0)
#define WRITELDS(pp) do { const int wb = (pp) * 10240 + wr_ints;          \
        *(i32x4*)&smem[wb]        = pack8(La0, La1);                      \
        *(i32x4*)&smem[wb + 2048] = pack8(Lr0 + Lr2, Lr1 + Lr3);          \
        *(i32x4*)&smem[wb + 4096] = pack8(Lz0 + Lz2, Lz1 + Lz3);          \
        *(i32x4*)&smem[wb + 6144] = pack8(Ln0, Ln1);                      \
        *(i32x4*)&smem[wb + 8192] = pack8(Lh0, Lh1); } while (0)
#define COMPUTE(pp) do {                                                  \
        const int cb = (pp) * 10240;                                      \
        const bf16x8* Af = (const bf16x8*)&smem[cb];                      \
        const bf16x8* Br = (const bf16x8*)&smem[cb + 2048];               \
        const bf16x8* Bz = (const bf16x8*)&smem[cb + 4096];               \
        const bf16x8* Bn = (const bf16x8*)&smem[cb + 6144];               \
        const bf16x8* Bh = (const bf16x8*)&smem[cb + 8192];               \
        bf16x8 afr[4];                                                    \
        _Pragma("unroll")                                                 \
        for (int mf = 0; mf < 4; ++mf)                                    \
            afr[mf] = Af[(wm * 4 + mf) * 64 + lane];                      \
        _Pragma("unroll")                                                 \
        for (int nf = 0; nf < 2; ++nf) {                                  \
            const int bi = (wn * 2 + nf) * 64 + lane;                     \
            bf16x8 fr = Br[bi], fz = Bz[bi], fn = Bn[bi], fh = Bh[bi];    \
            _Pragma("unroll")                                             \
            for (int mf = 0; mf < 4; ++mf) {                              \
                accR[mf][nf] = __builtin_amdgcn_mfma_f32_16x16x32_bf16(afr[mf], fr, accR[mf][nf], 0, 0, 0); \
                accZ[mf][nf] = __builtin_amdgcn_mfma_f32_16x16x32_bf16(afr[mf], fz, accZ[mf][nf], 0, 0, 0); \
                accN[mf][nf] = __builtin_amdgcn_mfma_f32_16x16x32_bf16(afr[mf], fn, accN[mf][nf], 0, 0, 0); \
                accH[mf][nf] = __builtin_amdgcn_mfma_f32_16x16x32_bf16(afr[mf], fh, accH[mf][nf], 0, 0, 0); \
            }                                                             \
        } } while (0)
    LOADREGS(0);
    WRITELDS(0);
    __syncthreads();
#pragma unroll 1
    for (int s = 0; s < 128; ++s) {
        if (s + 1 < 128) LOADREGS(s + 1);
        COMPUTE(s & 1);
        if (s + 1 < 128) { WRITELDS((s + 1) & 1); __syncthreads(); }
    }
    const int r4 = (lane >> 4) * 4;
    const int cn = lane & 15;
#pragma unroll
    for (int nf = 0; nf < 2; ++nf) {
        const int h = h0 + wn * 32 + nf * 16 + cn;
        const float br = b_ir[h] + b_hr[h];
        const float bz = b_iz[h] + b_hz[h];
        const float bn = b_in[h];
        const float bh = b_hn[h];
#pragma unroll
        for (int mf = 0; mf < 4; ++mf) {
            const int brow = b0 + wm * 64 + mf * 16 + r4;
#pragma unroll
            for (int j = 0; j < 4; ++j) {
                const size_t idx = (size_t)(brow + j) * H_DIM + h;
                const float r = sigmoidf_(accR[mf][nf][j] + br);
                const float z = sigmoidf_(accZ[mf][nf][j] + bz);
                const float n = sigmoidf_(accN[mf][nf][j] + bn + r * (accH[mf][nf][j] + bh));
                out[idx] = (1.0f - z) * hidden[idx] + z * n;
            }
        }
    }
#undef LOADREGS
#undef WRITELDS
#undef COMPUTE
}

extern "C" void kernel_launch(void* const* d_in, const int* in_sizes, int n_in,
                              void* d_out, int out_size, void* d_ws, size_t ws_size,
                              hipStream_t stream) {
    const float* input  = (const float*)d_in[0];
    const float* hidden = (const float*)d_in[1];
    const float* w_ir = (const float*)d_in[2];  const float* b_ir = (const float*)d_in[3];
    const float* w_iz = (const float*)d_in[4];  const float* b_iz = (const float*)d_in[5];
    const float* w_in = (const float*)d_in[6];  const float* b_in = (const float*)d_in[7];
    const float* w_hr = (const float*)d_in[8];  const float* b_hr = (const float*)d_in[9];
    const float* w_hz = (const float*)d_in[10]; const float* b_hz = (const float*)d_in[11];
    const float* w_hn = (const float*)d_in[12]; const float* b_hn = (const float*)d_in[13];
    float* out = (float*)d_out;

    if (ws_size >= WS_NEED) {
        char* ws = (char*)d_ws;
        prep_w_t<<<dim3(8192, 4), dim3(256), 0, stream>>>(
            w_ir, w_hr, w_iz, w_hz, w_in, w_hn, ws);
        prep_a_t<<<dim3(16384), dim3(256), 0, stream>>>(input, ws + WS_A);
        gru_bf16<<<dim3((B_DIM / BM) * (H_DIM / GBN)), dim3(THREADS), 0, stream>>>(
            ws + WS_A, ws + WS_WR, ws + WS_WZ, ws + WS_WN, ws + WS_WH,
            hidden, b_ir, b_iz, b_in, b_hr, b_hz, b_hn, out);
    } else {
        gru_fused_f32<<<dim3(2048), dim3(THREADS), 0, stream>>>(
            input, hidden, w_ir, b_ir, w_iz, b_iz, w_in, b_in,
            w_hr, b_hr, w_hz, b_hz, w_hn, b_hn, out);
    }
}

// Round 10
// 998.735 us; speedup vs baseline: 1.4415x; 1.0148x over previous
//
#include <hip/hip_runtime.h>
#include <hip/hip_bf16.h>

// out = (1-z)*hidden + z*n
//   r = sig(in·(w_ir+w_hr)^T + b_ir+b_hr)
//   z = sig(in·(w_iz+w_hz)^T + b_iz+b_hz)
//   n = sig(in·w_in^T + b_in + r*(in·w_hn^T + b_hn))
// Fast path: prepass folds/converts weights+input to bf16 in d_ws in LDS-
// fragment order (every global_load_lds reads 1KB contiguous -> round-8 win),
// then a 4-cluster fused GEMM with ONE barrier per K-tile, reads rotated one
// cluster ahead via counted lgkmcnt. Round 10 fix: separate afA (mh0) / afB
// (mh1) register sets so the rotated RD_AF(mh1) cannot clobber the operands
// of the still-pending mh0 MFMA cluster (round-9 correctness bug).
// Fallback (ws too small): round-1 fp32-staged kernel (known passing).

#define THREADS 512
#define B_DIM 8192
#define D_DIM 4096
#define H_DIM 4096
#define BM 256
#define GBN 64              // per-gate output cols per block
#define BK 64
#define NT (D_DIM / BK)     // 64 K-tiles
#define DBUF 65536          // bytes per LDS buffer: A 32KB + 4x8KB B

// ws layout (bytes)
#define WS_WR 0
#define WS_WZ 33554432
#define WS_WN 67108864
#define WS_WH 100663296
#define WS_A  134217728
#define WS_NEED 201326592ULL

typedef __attribute__((ext_vector_type(8))) short bf16x8;
typedef __attribute__((ext_vector_type(4))) float f32x4;
typedef __attribute__((ext_vector_type(4))) int i32x4;

__device__ __forceinline__ unsigned f2bf(float f) {
    union { float f; unsigned u; } v; v.f = f;
    return (v.u + 0x7FFFu + ((v.u >> 16) & 1u)) >> 16;   // RNE
}
__device__ __forceinline__ unsigned pk(float a, float b) {
    return (f2bf(a) & 0xFFFFu) | (f2bf(b) << 16);
}
__device__ __forceinline__ i32x4 pack8(float4 x, float4 y) {
    i32x4 r;
    r[0] = (int)pk(x.x, x.y); r[1] = (int)pk(x.z, x.w);
    r[2] = (int)pk(y.x, y.y); r[3] = (int)pk(y.z, y.w);
    return r;
}
__device__ __forceinline__ float sigmoidf_(float x) {
    return 1.0f / (1.0f + __expf(-x));
}
__device__ __forceinline__ void gld16(const void* g, void* l) {
    __builtin_amdgcn_global_load_lds(
        (const __attribute__((address_space(1))) unsigned*)g,
        (__attribute__((address_space(3))) unsigned*)l, 16, 0, 0);
}

// ---------------- prepass: fold/convert + permute into fragment order -----
// W gate layout (32MB each): [hblk 0..63][t 0..63][nfr 0..3][kk 0..1][C 0..3][R 0..15][16B]
// A layout (64MB): [bblk 0..31][t 0..63][mfr 0..15][kk][C][R][16B]
__global__ __launch_bounds__(256) void prep_w_t(
    const float* __restrict__ ir, const float* __restrict__ hr,
    const float* __restrict__ iz, const float* __restrict__ hz,
    const float* __restrict__ inw, const float* __restrict__ hn,
    char* __restrict__ wsbase)
{
    const int tx = threadIdx.x;
    const int R = tx & 15;
    const int c8loc = tx >> 4;
    const int bx = blockIdx.x;
    const int c8blk = bx & 31;
    const int hgrp = bx >> 5;
    const int gy = blockIdx.y;
    const int h  = hgrp * 16 + R;
    const int c8 = c8blk * 16 + c8loc;

    const float* s1 = (gy == 0) ? ir : (gy == 1) ? iz : (gy == 2) ? inw : hn;
    const size_t fi = ((size_t)h * 512 + c8) * 2;   // float4 index
    const float4* p1 = (const float4*)s1;
    float4 a0 = p1[fi], a1 = p1[fi + 1];
    if (gy < 2) {
        const float4* p2 = (const float4*)((gy == 0) ? hr : hz);
        a0 = a0 + p2[fi];
        a1 = a1 + p2[fi + 1];
    }
    const i32x4 v = pack8(a0, a1);
    const int hblk = h >> 6, nfr = (h >> 4) & 3;
    const int t = c8 >> 3, K = (c8 >> 2) & 1, C = c8 & 3;
    const size_t addr = (size_t)gy * 33554432 + (size_t)hblk * 524288
                      + (size_t)t * 8192 + nfr * 2048 + K * 1024 + C * 256 + R * 16;
    *(i32x4*)(wsbase + addr) = v;
}

__global__ __launch_bounds__(256) void prep_a_t(const float* __restrict__ in,
                                                char* __restrict__ abase)
{
    const int tx = threadIdx.x;
    const int R = tx & 15;
    const int c8loc = tx >> 4;
    const int bx = blockIdx.x;
    const int c8blk = bx & 31;
    const int bgrp = bx >> 5;
    const int b  = bgrp * 16 + R;
    const int c8 = c8blk * 16 + c8loc;

    const size_t fi = ((size_t)b * 512 + c8) * 2;
    const float4* p = (const float4*)in;
    const i32x4 v = pack8(p[fi], p[fi + 1]);
    const int bblk = b >> 8, mfr = (b >> 4) & 15;
    const int t = c8 >> 3, K = (c8 >> 2) & 1, C = c8 & 3;
    const size_t addr = (size_t)bblk * 2097152 + (size_t)t * 32768
                      + mfr * 2048 + K * 1024 + C * 256 + R * 16;
    *(i32x4*)(abase + addr) = v;
}

// ---------------- main bf16 kernel (1 barrier/tile, rotated reads) --------
// LDS per buffer (64 KB):
//   A  [0, 32K):  frag(mfr 0..15, kk 0..1) at (mfr*2+kk)*1024
//   Bg [32K+g*8K, +8K): frag(nfr 0..3, kk) at (nfr*2+kk)*1024
// Frag = 16 rows x 32 k bf16, 1 KB, lane-linear -> gld16 and ds_read_b128
// both conflict-free. Staging sources fragment-ordered in ws (round 8).
//
// Per K-tile t (reads dbuf p=t&1; stages tile t+1 into dbuf p^1):
//   R1 {afA=mh0(8), fb01(4)} + STAGE_A | SB | R2 {fb23(4)} + STAGE_B
//   lgkmcnt(4)  -> R1 done (R2 in flight)        | MFMA1 (afA x g01)
//   lgkmcnt(0)  -> R2 done (hid under MFMA1)     | R3 {afB=mh1(8)} | MFMA2 (afA x g23)
//   lgkmcnt(0)  -> R3 done (interleaved w MFMA2) | MFMA3 (afB x g01) MFMA4 (afB x g23)
//   vmcnt(0) ; s_barrier   (ONLY barrier in the tile)
// Hazard proof: stages into buf p^1 are issued only after the boundary
// barrier, and every wave's reads of buf p^1 (tile t-1) completed (lgkm-
// waited) before it arrived at that barrier. Reads of buf p are covered by
// the per-wave vmcnt(0) + barrier (all waves drained their own stages).
// Register proof: afA stays live until MFMA2 retires; R3 writes afB only.
__global__ __launch_bounds__(THREADS, 2) void gru_bf16(
    const char* __restrict__ Abf, const char* __restrict__ Wr,
    const char* __restrict__ Wz, const char* __restrict__ Wn,
    const char* __restrict__ Wh,
    const float* __restrict__ hidden,
    const float* __restrict__ b_ir, const float* __restrict__ b_iz,
    const float* __restrict__ b_in, const float* __restrict__ b_hr,
    const float* __restrict__ b_hz, const float* __restrict__ b_hn,
    float* __restrict__ out)
{
    __shared__ __attribute__((aligned(128))) char smem[2 * DBUF];

    const int tid  = threadIdx.x;
    const int lane = tid & 63;
    const int wid  = tid >> 6;
    const int wm   = wid >> 2;     // 0..1 : M-half (128 rows)
    const int wn   = wid & 3;      // 0..3 : 16-col slice (nfr = wn)

    // linear, b-fastest: consecutive blocks share the weight panel; A L3-hot.
    const int nb   = (int)blockIdx.x;
    const int bblk = nb & 31;       // 32 b-blocks
    const int hblk = nb >> 5;       // 64 h-blocks
    const int b0 = bblk * BM;
    const int h0 = hblk * GBN;

    // staging roles (per wave): A-frags mfr = 2w, 2w+1 (4KB contiguous);
    // B gate sg = w>>1, nfr = (w&1)*2, +1 (4KB contiguous).
    const int sg  = wid >> 1;
    const int sn0 = (wid & 1) * 2;
    const char* gWsel = (sg == 0) ? Wr : (sg == 1) ? Wz : (sg == 2) ? Wn : Wh;
    const char* pA = Abf + (size_t)bblk * 2097152 + (size_t)(2 * wid) * 2048 + (lane << 4);
    const char* pB = gWsel + (size_t)hblk * 524288 + (size_t)sn0 * 2048 + (lane << 4);
    const int dA = (2 * wid) * 2048;
    const int dB = 32768 + sg * 8192 + sn0 * 2048;

    f32x4 acc[4][8];
#pragma unroll
    for (int g = 0; g < 4; ++g)
#pragma unroll
        for (int m = 0; m < 8; ++m) acc[g][m] = (f32x4)0.0f;

#define STAGE_A(t, d) do { const size_t ko = (size_t)(t) * 32768;              \
        gld16(pA + ko,        smem + (d) + dA);                                \
        gld16(pA + ko + 1024, smem + (d) + dA + 1024);                         \
        gld16(pA + ko + 2048, smem + (d) + dA + 2048);                         \
        gld16(pA + ko + 3072, smem + (d) + dA + 3072);                         \
    } while (0)

#define STAGE_B(t, d) do { const size_t ko = (size_t)(t) * 8192;               \
        gld16(pB + ko,        smem + (d) + dB);                                \
        gld16(pB + ko + 1024, smem + (d) + dB + 1024);                         \
        gld16(pB + ko + 2048, smem + (d) + dB + 2048);                         \
        gld16(pB + ko + 3072, smem + (d) + dB + 3072);                         \
    } while (0)

    // read A-fragments of M-quarter mhq into register set dst
#define RD_AF(dst, mhq) do {                                                   \
        _Pragma("unroll")                                                      \
        for (int mf = 0; mf < 4; ++mf)                                         \
            _Pragma("unroll")                                                  \
            for (int kk = 0; kk < 2; ++kk)                                     \
                dst[mf][kk] = *(const bf16x8*)(cb + ((wm * 8 + (mhq) * 4 + mf) * 2 + kk) * 1024 + (lane << 4)); \
    } while (0)

#define RD_FB(g) do {                                                          \
        _Pragma("unroll")                                                      \
        for (int kk = 0; kk < 2; ++kk)                                         \
            fb[g][kk] = *(const bf16x8*)(cb + 32768 + (g) * 8192 + (wn * 2 + kk) * 1024 + (lane << 4)); \
    } while (0)

#define MM(acc_, a_, b_) acc_ = __builtin_amdgcn_mfma_f32_16x16x32_bf16(a_, b_, acc_, 0, 0, 0)

    // one 16-MFMA cluster: gates g0_,g0_+1 x A-set src (quarter ab_)
#define MFMA_CL(src, g0_, ab_) do {                                            \
        __builtin_amdgcn_s_setprio(1);                                         \
        _Pragma("unroll")                                                      \
        for (int g = (g0_); g < (g0_) + 2; ++g)                                \
            _Pragma("unroll")                                                  \
            for (int mf = 0; mf < 4; ++mf)                                     \
                _Pragma("unroll")                                              \
                for (int kk = 0; kk < 2; ++kk)                                 \
                    MM(acc[g][(ab_) * 4 + mf], src[mf][kk], fb[g][kk]);        \
        __builtin_amdgcn_s_setprio(0);                                         \
    } while (0)

#define SB0 __builtin_amdgcn_sched_barrier(0)

    // ---- prologue: stage tile 0 into dbuf0 ----
    STAGE_A(0, 0);
    STAGE_B(0, 0);
    asm volatile("s_waitcnt vmcnt(0)" ::: "memory");
    __builtin_amdgcn_s_barrier();

#pragma unroll 1
    for (int t = 0; t < NT; ++t) {
        const int p = t & 1;
        const char* cb = smem + p * DBUF;
        const int d = (p ^ 1) * DBUF;
        const bool stg = (t < NT - 1);
        bf16x8 afA[4][2], afB[4][2], fb[4][2];

        // ---- R1 (12 ds_read: afA = mh0, fb01) + stage A(t+1) ----
        RD_AF(afA, 0);
        RD_FB(0); RD_FB(1);
        if (stg) STAGE_A(t + 1, d);
        SB0;                                            // pin R1 before R2
        // ---- R2 (4 ds_read: fb23) + stage B(t+1) ----
        RD_FB(2); RD_FB(3);
        if (stg) STAGE_B(t + 1, d);
        asm volatile("s_waitcnt lgkmcnt(4)" ::: "memory");   // R1 done, R2 in flight
        SB0;
        MFMA_CL(afA, 0, 0);                             // mh0 x g0,g1  (hides R2)
        asm volatile("s_waitcnt lgkmcnt(0)" ::: "memory");   // R2 done
        SB0;
        // ---- R3 (8 ds_read: afB = mh1) — interleaves with MFMA2 (distinct regs) ----
        RD_AF(afB, 1);
        MFMA_CL(afA, 2, 0);                             // mh0 x g2,g3 (afA still live)
        asm volatile("s_waitcnt lgkmcnt(0)" ::: "memory");   // R3 done
        SB0;
        MFMA_CL(afB, 0, 1);                             // mh1 x g0,g1
        MFMA_CL(afB, 2, 1);                             // mh1 x g2,g3
        // ---- tile boundary: publish t+1's stages; ONLY barrier ----
        if (stg) { asm volatile("s_waitcnt vmcnt(0)" ::: "memory"); }
        SB0;
        __builtin_amdgcn_s_barrier();
    }

    // ---- epilogue: biases + gate math + combine, fp32 out ----
    const int r4 = (lane >> 4) * 4;
    const int cn = lane & 15;
    {
        const int h = h0 + wn * 16 + cn;
        const float br = b_ir[h] + b_hr[h];
        const float bz = b_iz[h] + b_hz[h];
        const float bn = b_in[h];
        const float bh = b_hn[h];
#pragma unroll
        for (int m = 0; m < 8; ++m) {
            const int brow = b0 + wm * 128 + m * 16 + r4;
#pragma unroll
            for (int j = 0; j < 4; ++j) {
                const size_t idx = (size_t)(brow + j) * H_DIM + h;
                const float r = sigmoidf_(acc[0][m][j] + br);
                const float z = sigmoidf_(acc[1][m][j] + bz);
                const float n = sigmoidf_(acc[2][m][j] + bn + r * (acc[3][m][j] + bh));
                out[idx] = (1.0f - z) * hidden[idx] + z * n;
            }
        }
    }
#undef STAGE_A
#undef STAGE_B
#undef RD_AF
#undef RD_FB
#undef MM
#undef MFMA_CL
#undef SB0
}

// ---------------- fallback: round-1 fp32-staged kernel (known passing) ----------------
__global__ __launch_bounds__(THREADS, 2) void gru_fused_f32(
    const float* __restrict__ input, const float* __restrict__ hidden,
    const float* __restrict__ w_ir, const float* __restrict__ b_ir,
    const float* __restrict__ w_iz, const float* __restrict__ b_iz,
    const float* __restrict__ w_in, const float* __restrict__ b_in,
    const float* __restrict__ w_hr, const float* __restrict__ b_hr,
    const float* __restrict__ w_hz, const float* __restrict__ b_hz,
    const float* __restrict__ w_hn, const float* __restrict__ b_hn,
    float* __restrict__ out)
{
    __shared__ int smem[2 * 10240];
    const int tid  = threadIdx.x;
    const int lane = tid & 63;
    const int wid  = tid >> 6;
    const int wm   = wid >> 2;
    const int wn   = wid & 3;
    const int bblk = blockIdx.x & 63;
    const int hblk = blockIdx.x >> 6;
    const int b0 = bblk * 128;
    const int h0 = hblk * 128;
    const int srow = tid >> 2;
    const int sc   = tid & 3;
    const float4* gA  = (const float4*)(input + (size_t)(b0 + srow) * D_DIM + sc * 8);
    const size_t woff = (size_t)(h0 + srow) * D_DIM + sc * 8;
    const float4* gIr = (const float4*)(w_ir + woff);
    const float4* gHr = (const float4*)(w_hr + woff);
    const float4* gIz = (const float4*)(w_iz + woff);
    const float4* gHz = (const float4*)(w_hz + woff);
    const float4* gIn = (const float4*)(w_in + woff);
    const float4* gHn = (const float4*)(w_hn + woff);
    const int wr_ints = (srow >> 4) * 256 + ((sc * 16 + (srow & 15)) * 4);

    f32x4 accR[4][2], accZ[4][2], accN[4][2], accH[4][2];
#pragma unroll
    for (int mf = 0; mf < 4; ++mf)
#pragma unroll
        for (int nf = 0; nf < 2; ++nf) {
            accR[mf][nf] = (f32x4)0.0f; accZ[mf][nf] = (f32x4)0.0f;
            accN[mf][nf] = (f32x4)0.0f; accH[mf][nf] = (f32x4)0.0f;
        }
    float4 La0, La1, Lr0, Lr1, Lr2, Lr3, Lz0, Lz1, Lz2, Lz3, Ln0, Ln1, Lh0, Lh1;
#define LOADREGS(s) do { const int o = (s) * 8;                          \
        La0 = gA[o];  La1 = gA[o + 1];                                   \
        Lr0 = gIr[o]; Lr1 = gIr[o + 1]; Lr2 = gHr[o]; Lr3 = gHr[o + 1];  \
        Lz0 = gIz[o]; Lz1 = gIz[o + 1]; Lz2 = gHz[o]; Lz3 = gHz[o + 1];  \
        Ln0 = gIn[o]; Ln1 = gIn[o + 1];                                  \
        Lh0 = gHn[o]; Lh1 = gHn[o + 1]; } while (0)
#define WRITELDS(pp) do { const int wb = (pp) * 10240 + wr_ints;          \
        *(i32x4*)&smem[wb]        = pack8(La0, La1);                      \
        *(i32x4*)&smem[wb + 2048] = pack8(Lr0 + Lr2, Lr1 + Lr3);          \
        *(i32x4*)&smem[wb + 4096] = pack8(Lz0 + Lz2, Lz1 + Lz3);          \
        *(i32x4*)&smem[wb + 6144] = pack8(Ln0, Ln1);                      \
        *(i32x4*)&smem[wb + 8192] = pack8(Lh0, Lh1); } while (0)
#define COMPUTE(pp) do {                                                  \
        const int cb = (pp) * 10240;                                      \
        const bf16x8* Af = (const bf16x8*)&smem[cb];                      \
        const bf16x8* Br = (const bf16x8*)&smem[cb + 2048];               \
        const bf16x8* Bz = (const bf16x8*)&smem[cb + 4096];               \
        const bf16x8* Bn = (const bf16x8*)&smem[cb + 6144];               \
        const bf16x8* Bh = (const bf16x8*)&smem[cb + 8192];               \
        bf16x8 afr[4];                                                    \
        _Pragma("unroll")                                                 \
        for (int mf = 0; mf < 4; ++mf)                                    \
            afr[mf] = Af[(wm * 4 + mf) * 64 + lane];                      \
        _Pragma("unroll")                                                 \
        for (int nf = 0; nf < 2; ++nf) {                                  \
            const int bi = (wn * 2 + nf) * 64 + lane;                     \
            bf16x8 fr = Br[bi], fz = Bz[bi], fn = Bn[bi], fh = Bh[bi];    \
            _Pragma("unroll")                                             \
            for (int mf = 0; mf < 4; ++mf) {                              \
                accR[mf][nf] = __builtin_amdgcn_mfma_f32_16x16x32_bf16(afr[mf], fr, accR[mf][nf], 0, 0, 0); \
                accZ[mf][nf] = __builtin_amdgcn_mfma_f32_16x16x32_bf16(afr[mf], fz, accZ[mf][nf], 0, 0, 0); \
                accN[mf][nf] = __builtin_amdgcn_mfma_f32_16x16x32_bf16(afr[mf], fn, accN[mf][nf], 0, 0, 0); \
                accH[mf][nf] = __builtin_amdgcn_mfma_f32_16x16x32_bf16(afr[mf], fh, accH[mf][nf], 0, 0, 0); \
            }                                                             \
        } } while (0)
    LOADREGS(0);
    WRITELDS(0);
    __syncthreads();
#pragma unroll 1
    for (int s = 0; s < 128; ++s) {
        if (s + 1 < 128) LOADREGS(s + 1);
        COMPUTE(s & 1);
        if (s + 1 < 128) { WRITELDS((s + 1) & 1); __syncthreads(); }
    }
    const int r4 = (lane >> 4) * 4;
    const int cn = lane & 15;
#pragma unroll
    for (int nf = 0; nf < 2; ++nf) {
        const int h = h0 + wn * 32 + nf * 16 + cn;
        const float br = b_ir[h] + b_hr[h];
        const float bz = b_iz[h] + b_hz[h];
        const float bn = b_in[h];
        const float bh = b_hn[h];
#pragma unroll
        for (int mf = 0; mf < 4; ++mf) {
            const int brow = b0 + wm * 64 + mf * 16 + r4;
#pragma unroll
            for (int j = 0; j < 4; ++j) {
                const size_t idx = (size_t)(brow + j) * H_DIM + h;
                const float r = sigmoidf_(accR[mf][nf][j] + br);
                const float z = sigmoidf_(accZ[mf][nf][j] + bz);
                const float n = sigmoidf_(accN[mf][nf][j] + bn + r * (accH[mf][nf][j] + bh));
                out[idx] = (1.0f - z) * hidden[idx] + z * n;
            }
        }
    }
#undef LOADREGS
#undef WRITELDS
#undef COMPUTE
}

extern "C" void kernel_launch(void* const* d_in, const int* in_sizes, int n_in,
                              void* d_out, int out_size, void* d_ws, size_t ws_size,
                              hipStream_t stream) {
    const float* input  = (const float*)d_in[0];
    const float* hidden = (const float*)d_in[1];
    const float* w_ir = (const float*)d_in[2];  const float* b_ir = (const float*)d_in[3];
    const float* w_iz = (const float*)d_in[4];  const float* b_iz = (const float*)d_in[5];
    const float* w_in = (const float*)d_in[6];  const float* b_in = (const float*)d_in[7];
    const float* w_hr = (const float*)d_in[8];  const float* b_hr = (const float*)d_in[9];
    const float* w_hz = (const float*)d_in[10]; const float* b_hz = (const float*)d_in[11];
    const float* w_hn = (const float*)d_in[12]; const float* b_hn = (const float*)d_in[13];
    float* out = (float*)d_out;

    if (ws_size >= WS_NEED) {
        char* ws = (char*)d_ws;
        prep_w_t<<<dim3(8192, 4), dim3(256), 0, stream>>>(
            w_ir, w_hr, w_iz, w_hz, w_in, w_hn, ws);
        prep_a_t<<<dim3(16384), dim3(256), 0, stream>>>(input, ws + WS_A);
        gru_bf16<<<dim3((B_DIM / BM) * (H_DIM / GBN)), dim3(THREADS), 0, stream>>>(
            ws + WS_A, ws + WS_WR, ws + WS_WZ, ws + WS_WN, ws + WS_WH,
            hidden, b_ir, b_iz, b_in, b_hr, b_hz, b_hn, out);
    } else {
        gru_fused_f32<<<dim3(2048), dim3(THREADS), 0, stream>>>(
            input, hidden, w_ir, b_ir, w_iz, b_iz, w_in, b_in,
            w_hr, b_hr, w_hz, b_hz, w_hn, b_hn, out);
    }
}